// Round 1
// baseline (1065.022 us; speedup 1.0000x reference)
//
#include <hip/hip_runtime.h>

// Problem constants (B=8, T=2048, C=512, KEY=512)
#define BATCH 8
#define TSEQ  2048
#define CDIM  512
#define MTOK  (BATCH*TSEQ)   // 16384

typedef __attribute__((ext_vector_type(8))) short bf16x8;
typedef __attribute__((ext_vector_type(4))) float f32x4;

__device__ __forceinline__ unsigned short f2bf(float f) {
    union { float f; unsigned int u; } v; v.f = f;
    unsigned int r = v.u + 0x7FFF + ((v.u >> 16) & 1);
    return (unsigned short)(r >> 16);
}

// 16x32 MFMA operand fragment: 16 rows (rowStart+lane16) x 32 k (k0 + quad*8 + j)
// Works for both A (rows = m) and B (rows = n, reading W/K row-major == B^T).
__device__ __forceinline__ bf16x8 load_frag(const unsigned short* p, int rowStart,
                                            int ld, int k0, int lane16, int quad) {
    return *(const bf16x8*)(p + (size_t)(rowStart + lane16) * ld + k0 + quad * 8);
}

__device__ __forceinline__ f32x4 fzero() { f32x4 z = {0.f, 0.f, 0.f, 0.f}; return z; }

// ---------------- Stage 1: conversions ----------------
// one thread = 4 floats. Also writes x into out[:, :, 0:512].
__global__ __launch_bounds__(256) void k_convert_x(const float* __restrict__ x,
                                                   unsigned short* __restrict__ xb,
                                                   float* __restrict__ out) {
    int i = blockIdx.x * blockDim.x + threadIdx.x;      // float4 index
    float4 v = ((const float4*)x)[i];
    ushort4 o;
    o.x = f2bf(v.x); o.y = f2bf(v.y); o.z = f2bf(v.z); o.w = f2bf(v.w);
    ((ushort4*)xb)[i] = o;
    int e = i * 4;
    int row = e >> 9;          // /512
    int c   = e & 511;
    *(float4*)(out + (size_t)row * 1024 + c) = v;
}

__global__ __launch_bounds__(256) void k_convert_w(const float* __restrict__ w,
                                                   unsigned short* __restrict__ wb) {
    int i = blockIdx.x * blockDim.x + threadIdx.x;
    float4 v = ((const float4*)w)[i];
    ushort4 o;
    o.x = f2bf(v.x); o.y = f2bf(v.y); o.z = f2bf(v.z); o.w = f2bf(v.w);
    ((ushort4*)wb)[i] = o;
}

// ---------------- Stage 2: QKV projection ----------------
// out = xb[16384,512] @ W^T + bias. mode 0/1: row-major bf16 [16384,512].
// mode 2: transposed per-batch: Vt[b][n][t] (so PV B-operand is contiguous).
__global__ __launch_bounds__(256) void k_qkv(const unsigned short* __restrict__ xb,
                                             const unsigned short* __restrict__ wb,
                                             const float* __restrict__ bias,
                                             unsigned short* __restrict__ dst, int mode) {
    int m0 = blockIdx.x * 64, n0 = blockIdx.y * 64;
    int w = threadIdx.x >> 6, lane = threadIdx.x & 63;
    int quad = lane >> 4, lane16 = lane & 15;
    int nw = n0 + w * 16;

    f32x4 acc[4];
    for (int i = 0; i < 4; i++) acc[i] = fzero();

    for (int k = 0; k < CDIM; k += 32) {
        bf16x8 bfr = load_frag(wb, nw, CDIM, k, lane16, quad);
#pragma unroll
        for (int mt = 0; mt < 4; mt++) {
            bf16x8 afr = load_frag(xb, m0 + mt * 16, CDIM, k, lane16, quad);
            acc[mt] = __builtin_amdgcn_mfma_f32_16x16x32_bf16(afr, bfr, acc[mt], 0, 0, 0);
        }
    }

    int n = nw + lane16;
    float bv = bias[n];
#pragma unroll
    for (int mt = 0; mt < 4; mt++) {
#pragma unroll
        for (int r = 0; r < 4; r++) {
            int m = m0 + mt * 16 + quad * 4 + r;
            float val = acc[mt][r] + bv;
            if (mode < 2) {
                dst[(size_t)m * CDIM + n] = f2bf(val);
            } else {
                int b = m >> 11, t = m & (TSEQ - 1);
                dst[((size_t)b * CDIM + n) * TSEQ + t] = f2bf(val);
            }
        }
    }
}

// ---------------- Stage 3: column sums of exp(S) over q >= s ----------------
// S[q][s] = Q[q]·K[s]. Block computes a 64q x 64s tile; wave w owns 16 s-cols.
__global__ __launch_bounds__(256) void k_colsum(const unsigned short* __restrict__ Qb,
                                                const unsigned short* __restrict__ Kb,
                                                float* __restrict__ colsum) {
    int s0 = blockIdx.x * 64, q0 = blockIdx.y * 64, b = blockIdx.z;
    if (q0 + 63 < s0) return;  // fully masked tile
    int w = threadIdx.x >> 6, lane = threadIdx.x & 63;
    int quad = lane >> 4, lane16 = lane & 15;
    const unsigned short* Qp = Qb + (size_t)b * TSEQ * CDIM;
    const unsigned short* Kp = Kb + (size_t)b * TSEQ * CDIM;

    f32x4 acc[4];
    for (int i = 0; i < 4; i++) acc[i] = fzero();
    int sw = s0 + w * 16;

    for (int k = 0; k < CDIM; k += 32) {
        bf16x8 bk = load_frag(Kp, sw, CDIM, k, lane16, quad);
#pragma unroll
        for (int qt = 0; qt < 4; qt++) {
            bf16x8 aq = load_frag(Qp, q0 + qt * 16, CDIM, k, lane16, quad);
            acc[qt] = __builtin_amdgcn_mfma_f32_16x16x32_bf16(aq, bk, acc[qt], 0, 0, 0);
        }
    }

    const float scale = 0.044194173824159216f;  // 1/sqrt(512)
    int s = sw + lane16;
    float sum = 0.f;
#pragma unroll
    for (int qt = 0; qt < 4; qt++) {
#pragma unroll
        for (int r = 0; r < 4; r++) {
            int q = q0 + qt * 16 + quad * 4 + r;
            if (s <= q) sum += __expf(acc[qt][r] * scale);
        }
    }
    // reduce across the 4 lane-groups sharing lane16 (lanes l, l^16, l^32, l^48)
    sum += __shfl_xor(sum, 16);
    sum += __shfl_xor(sum, 32);
    if (quad == 0) atomicAdd(&colsum[b * TSEQ + s], sum);
}

// ---------------- Stage 4: attn = (exp(S)/colsum[s]) @ V ----------------
// Block: 32 q-rows, full 512 v-cols (wave w owns v-cols [w*128, w*128+128)).
__global__ __launch_bounds__(256) void k_attn(const unsigned short* __restrict__ Qb,
                                              const unsigned short* __restrict__ Kb,
                                              const unsigned short* __restrict__ Vt,
                                              const float* __restrict__ colsum,
                                              float* __restrict__ out) {
    __shared__ unsigned short P[32 * 64];  // P tile, row-major [q][s]
    int b = blockIdx.y;
    int q0 = blockIdx.x * 32;
    int w = threadIdx.x >> 6, lane = threadIdx.x & 63;
    int quad = lane >> 4, lane16 = lane & 15;
    const unsigned short* Qp = Qb + (size_t)b * TSEQ * CDIM;
    const unsigned short* Kp = Kb + (size_t)b * TSEQ * CDIM;
    const unsigned short* Vp = Vt + (size_t)b * CDIM * TSEQ;
    const float* csp = colsum + b * TSEQ;

    f32x4 acc[2][8];
    for (int i = 0; i < 2; i++)
        for (int j = 0; j < 8; j++) acc[i][j] = fzero();

    const float scale = 0.044194173824159216f;
    int nsb = (q0 + 32 + 63) / 64;  // s-blocks covering s <= q0+31

    for (int sb = 0; sb < nsb; sb++) {
        int s0 = sb * 64;
        int sw = s0 + w * 16;

        // S tile [32 x 64]: wave w computes s-cols [sw, sw+16)
        f32x4 sacc[2];
        sacc[0] = fzero(); sacc[1] = fzero();
        for (int k = 0; k < CDIM; k += 32) {
            bf16x8 bk = load_frag(Kp, sw, CDIM, k, lane16, quad);
#pragma unroll
            for (int qt = 0; qt < 2; qt++) {
                bf16x8 aq = load_frag(Qp, q0 + qt * 16, CDIM, k, lane16, quad);
                sacc[qt] = __builtin_amdgcn_mfma_f32_16x16x32_bf16(aq, bk, sacc[qt], 0, 0, 0);
            }
        }

        int s = sw + lane16;
        float inv_cs = 1.0f / csp[s];

        __syncthreads();  // previous iteration's P reads complete
#pragma unroll
        for (int qt = 0; qt < 2; qt++) {
#pragma unroll
            for (int r = 0; r < 4; r++) {
                int q = q0 + qt * 16 + quad * 4 + r;
                float p = (s <= q) ? __expf(sacc[qt][r] * scale) * inv_cs : 0.0f;
                P[(qt * 16 + quad * 4 + r) * 64 + w * 16 + lane16] = f2bf(p);
            }
        }
        __syncthreads();

        // acc += P[32x64] @ V[s0:s0+64][w*128 : w*128+128]
#pragma unroll
        for (int kk = 0; kk < 64; kk += 32) {
            bf16x8 ap0 = *(const bf16x8*)(&P[(0 * 16 + lane16) * 64 + kk + quad * 8]);
            bf16x8 ap1 = *(const bf16x8*)(&P[(1 * 16 + lane16) * 64 + kk + quad * 8]);
#pragma unroll
            for (int vt = 0; vt < 8; vt++) {
                bf16x8 bv = *(const bf16x8*)(Vp + (size_t)(w * 128 + vt * 16 + lane16) * TSEQ
                                             + s0 + kk + quad * 8);
                acc[0][vt] = __builtin_amdgcn_mfma_f32_16x16x32_bf16(ap0, bv, acc[0][vt], 0, 0, 0);
                acc[1][vt] = __builtin_amdgcn_mfma_f32_16x16x32_bf16(ap1, bv, acc[1][vt], 0, 0, 0);
            }
        }
    }

    // epilogue: out[b][q][512 + vcol]
#pragma unroll
    for (int qt = 0; qt < 2; qt++) {
#pragma unroll
        for (int vt = 0; vt < 8; vt++) {
#pragma unroll
            for (int r = 0; r < 4; r++) {
                int q = q0 + qt * 16 + quad * 4 + r;
                int col = 512 + w * 128 + vt * 16 + lane16;
                out[((size_t)b * TSEQ + q) * 1024 + col] = acc[qt][vt][r];
            }
        }
    }
}

extern "C" void kernel_launch(void* const* d_in, const int* in_sizes, int n_in,
                              void* d_out, int out_size, void* d_ws, size_t ws_size,
                              hipStream_t stream) {
    const float* x  = (const float*)d_in[0];
    const float* Wq = (const float*)d_in[1];
    const float* bq = (const float*)d_in[2];
    const float* Wk = (const float*)d_in[3];
    const float* bk = (const float*)d_in[4];
    const float* Wv = (const float*)d_in[5];
    const float* bv = (const float*)d_in[6];
    float* out = (float*)d_out;

    char* ws = (char*)d_ws;
    size_t off = 0;
    auto alloc = [&](size_t bytes) -> void* {
        void* p = ws + off;
        off += (bytes + 255) & ~(size_t)255;
        return p;
    };
    unsigned short* xb  = (unsigned short*)alloc((size_t)MTOK * CDIM * 2);
    unsigned short* Wqb = (unsigned short*)alloc((size_t)CDIM * CDIM * 2);
    unsigned short* Wkb = (unsigned short*)alloc((size_t)CDIM * CDIM * 2);
    unsigned short* Wvb = (unsigned short*)alloc((size_t)CDIM * CDIM * 2);
    unsigned short* Qb  = (unsigned short*)alloc((size_t)MTOK * CDIM * 2);
    unsigned short* Kb  = (unsigned short*)alloc((size_t)MTOK * CDIM * 2);
    unsigned short* Vtb = (unsigned short*)alloc((size_t)MTOK * CDIM * 2);
    float* colsum = (float*)alloc((size_t)BATCH * TSEQ * 4);

    // Stage 1: conversions (+ copy x into out[:, :, 0:512])
    k_convert_x<<<(MTOK * CDIM / 4) / 256, 256, 0, stream>>>(x, xb, out);
    k_convert_w<<<(CDIM * CDIM / 4) / 256, 256, 0, stream>>>(Wq, Wqb);
    k_convert_w<<<(CDIM * CDIM / 4) / 256, 256, 0, stream>>>(Wk, Wkb);
    k_convert_w<<<(CDIM * CDIM / 4) / 256, 256, 0, stream>>>(Wv, Wvb);

    // Stage 2: QKV projections
    dim3 gq(MTOK / 64, CDIM / 64);
    k_qkv<<<gq, 256, 0, stream>>>(xb, Wqb, bq, Qb, 0);
    k_qkv<<<gq, 256, 0, stream>>>(xb, Wkb, bk, Kb, 1);
    k_qkv<<<gq, 256, 0, stream>>>(xb, Wvb, bv, Vtb, 2);

    // Stage 3: column sums of exp(S) (softmax over query axis)
    hipMemsetAsync(colsum, 0, (size_t)BATCH * TSEQ * 4, stream);
    k_colsum<<<dim3(TSEQ / 64, TSEQ / 64, BATCH), 256, 0, stream>>>(Qb, Kb, colsum);

    // Stage 4: attention output
    k_attn<<<dim3(TSEQ / 32, BATCH), 256, 0, stream>>>(Qb, Kb, Vtb, colsum, out);
}

// Round 2
// 571.993 us; speedup vs baseline: 1.8620x; 1.8620x over previous
//
#include <hip/hip_runtime.h>

// Problem constants (B=8, T=2048, C=512, KEY=512)
#define BATCH 8
#define TSEQ  2048
#define CDIM  512
#define MTOK  (BATCH*TSEQ)   // 16384
#define NTRI  528            // 32*33/2 triangular 64x64 tiles per batch

typedef __attribute__((ext_vector_type(8))) short bf16x8;
typedef __attribute__((ext_vector_type(4))) float f32x4;

__device__ __forceinline__ unsigned short f2bf(float f) {
    union { float f; unsigned int u; } v; v.f = f;
    unsigned int r = v.u + 0x7FFF + ((v.u >> 16) & 1);
    return (unsigned short)(r >> 16);
}
__device__ __forceinline__ float bfl(unsigned short u) {
    union { unsigned int i; float f; } v; v.i = ((unsigned int)u) << 16; return v.f;
}

__device__ __forceinline__ bf16x8 load_frag(const unsigned short* p, int rowStart,
                                            int ld, int k0, int lane16, int quad) {
    return *(const bf16x8*)(p + (size_t)(rowStart + lane16) * ld + k0 + quad * 8);
}

__device__ __forceinline__ f32x4 fzero() { f32x4 z = {0.f, 0.f, 0.f, 0.f}; return z; }

// async 16B global -> LDS (wave-uniform base + lane*16 layout)
__device__ __forceinline__ void gl2lds16(const void* g, void* l) {
    __builtin_amdgcn_global_load_lds(
        (const __attribute__((address_space(1))) unsigned int*)g,
        (__attribute__((address_space(3))) unsigned int*)l, 16, 0, 0);
}

// ---------------- Stage 1: conversions ----------------
__global__ __launch_bounds__(256) void k_convert_x(const float* __restrict__ x,
                                                   unsigned short* __restrict__ xb,
                                                   float* __restrict__ out) {
    int i = blockIdx.x * blockDim.x + threadIdx.x;      // float4 index
    float4 v = ((const float4*)x)[i];
    ushort4 o;
    o.x = f2bf(v.x); o.y = f2bf(v.y); o.z = f2bf(v.z); o.w = f2bf(v.w);
    ((ushort4*)xb)[i] = o;
    int e = i * 4;
    int row = e >> 9;          // /512
    int c   = e & 511;
    *(float4*)(out + (size_t)row * 1024 + c) = v;
}

__global__ __launch_bounds__(256) void k_convert_w(const float* __restrict__ w,
                                                   unsigned short* __restrict__ wb) {
    int i = blockIdx.x * blockDim.x + threadIdx.x;
    float4 v = ((const float4*)w)[i];
    ushort4 o;
    o.x = f2bf(v.x); o.y = f2bf(v.y); o.z = f2bf(v.z); o.w = f2bf(v.w);
    ((ushort4*)wb)[i] = o;
}

// ---------------- Stage 2: QKV projection ----------------
__global__ __launch_bounds__(256) void k_qkv(const unsigned short* __restrict__ xb,
                                             const unsigned short* __restrict__ wb,
                                             const float* __restrict__ bias,
                                             unsigned short* __restrict__ dst, int mode) {
    int m0 = blockIdx.x * 64, n0 = blockIdx.y * 64;
    int w = threadIdx.x >> 6, lane = threadIdx.x & 63;
    int quad = lane >> 4, lane16 = lane & 15;
    int nw = n0 + w * 16;

    f32x4 acc[4];
    for (int i = 0; i < 4; i++) acc[i] = fzero();

    for (int k = 0; k < CDIM; k += 32) {
        bf16x8 bfr = load_frag(wb, nw, CDIM, k, lane16, quad);
#pragma unroll
        for (int mt = 0; mt < 4; mt++) {
            bf16x8 afr = load_frag(xb, m0 + mt * 16, CDIM, k, lane16, quad);
            acc[mt] = __builtin_amdgcn_mfma_f32_16x16x32_bf16(afr, bfr, acc[mt], 0, 0, 0);
        }
    }

    int n = nw + lane16;
    float bv = bias[n];
#pragma unroll
    for (int mt = 0; mt < 4; mt++) {
#pragma unroll
        for (int r = 0; r < 4; r++) {
            int m = m0 + mt * 16 + quad * 4 + r;
            float val = acc[mt][r] + bv;
            if (mode < 2) {
                dst[(size_t)m * CDIM + n] = f2bf(val);
            } else {
                int b = m >> 11, t = m & (TSEQ - 1);
                dst[((size_t)b * CDIM + n) * TSEQ + t] = f2bf(val);
            }
        }
    }
}

// ---------------- Stage 3: S = QK^T over triangle; write P tiles + colsum ----
// P stored blocked: [b][tri(qt)+st][64q x 64s] row-major, bf16.
__global__ __launch_bounds__(256) void k_score(const unsigned short* __restrict__ Qb,
                                               const unsigned short* __restrict__ Kb,
                                               unsigned short* __restrict__ Pbuf,
                                               float* __restrict__ colsum) {
    __shared__ __align__(16) unsigned short Pt[64 * 64];
    int idx = blockIdx.x, b = blockIdx.y;
    // decode triangular index -> (qt, st), qt >= st
    int qt = (int)((sqrtf(8.0f * idx + 1.0f) - 1.0f) * 0.5f);
    while ((qt + 1) * (qt + 2) / 2 <= idx) qt++;
    while (qt * (qt + 1) / 2 > idx) qt--;
    int st = idx - qt * (qt + 1) / 2;
    int q0 = qt * 64, s0 = st * 64;

    int w = threadIdx.x >> 6, lane = threadIdx.x & 63;
    int quad = lane >> 4, lane16 = lane & 15;
    const unsigned short* Qp = Qb + (size_t)b * TSEQ * CDIM;
    const unsigned short* Kp = Kb + (size_t)b * TSEQ * CDIM;

    f32x4 acc[4];
    for (int i = 0; i < 4; i++) acc[i] = fzero();
    int sw = s0 + w * 16;

    for (int k = 0; k < CDIM; k += 32) {
        bf16x8 bk = load_frag(Kp, sw, CDIM, k, lane16, quad);
#pragma unroll
        for (int qi = 0; qi < 4; qi++) {
            bf16x8 aq = load_frag(Qp, q0 + qi * 16, CDIM, k, lane16, quad);
            acc[qi] = __builtin_amdgcn_mfma_f32_16x16x32_bf16(aq, bk, acc[qi], 0, 0, 0);
        }
    }

    const float scale = 0.044194173824159216f;  // 1/sqrt(512)
    int s = sw + lane16;
    float sum = 0.f;
#pragma unroll
    for (int qi = 0; qi < 4; qi++) {
#pragma unroll
        for (int r = 0; r < 4; r++) {
            int q = q0 + qi * 16 + quad * 4 + r;
            float p = 0.0f;
            if (s <= q) { p = __expf(acc[qi][r] * scale); sum += p; }
            Pt[(qi * 16 + quad * 4 + r) * 64 + w * 16 + lane16] = f2bf(p);
        }
    }
    sum += __shfl_xor(sum, 16);
    sum += __shfl_xor(sum, 32);
    if (quad == 0) atomicAdd(&colsum[b * TSEQ + s], sum);

    __syncthreads();
    // coalesced 16B writes of the tile to global (tile is contiguous 8KB)
    unsigned short* tile = Pbuf + ((size_t)b * NTRI + idx) * 4096;
    int t = threadIdx.x;
#pragma unroll
    for (int pass = 0; pass < 2; pass++) {
        int row = pass * 32 + (t >> 3);
        int col = (t & 7) * 8;
        *(uint4*)(tile + row * 64 + col) = *(const uint4*)(&Pt[row * 64 + col]);
    }
}

// ---------------- Stage 3b: invert colsum ----------------
__global__ __launch_bounds__(256) void k_invcs(float* __restrict__ cs) {
    int i = blockIdx.x * 256 + threadIdx.x;
    cs[i] = 1.0f / cs[i];
}

// ---------------- Stage 3c: Vn[v][s] = V[v][s] * inv_colsum[s] (in place) ---
__global__ __launch_bounds__(256) void k_vscale(unsigned short* __restrict__ Vt,
                                                const float* __restrict__ inv) {
    int idx = blockIdx.x * 256 + threadIdx.x;   // 16B unit (8 bf16)
    int s8  = idx & 255;                        // 2048/8 units per row
    int row = idx >> 8;                         // b*512 + v
    int b   = row >> 9;
    uint4 raw = ((const uint4*)Vt)[idx];
    const float* ip = inv + b * TSEQ + s8 * 8;
    unsigned int rr[4] = {raw.x, raw.y, raw.z, raw.w};
    unsigned int oo[4];
#pragma unroll
    for (int j = 0; j < 4; j++) {
        float f0 = bfl((unsigned short)(rr[j] & 0xffff)) * ip[j * 2];
        float f1 = bfl((unsigned short)(rr[j] >> 16))    * ip[j * 2 + 1];
        oo[j] = (unsigned int)f2bf(f0) | ((unsigned int)f2bf(f1) << 16);
    }
    uint4 o = {oo[0], oo[1], oo[2], oo[3]};
    ((uint4*)Vt)[idx] = o;
}

// ---------------- Stage 4: attn = P @ Vn^T (GEMM, LDS-staged) ----------------
// 64x64 output tile, BK=32. A = P (blocked tiles), B = Vn^T [v][s].
__global__ __launch_bounds__(256) void k_attn_gemm(const unsigned short* __restrict__ Pbuf,
                                                   const unsigned short* __restrict__ Vnt,
                                                   float* __restrict__ out) {
    __shared__ __align__(16) unsigned short As[64 * 32];
    __shared__ __align__(16) unsigned short Bs[64 * 32];
    int b  = blockIdx.z;
    int v0 = blockIdx.y * 64;
    int qt = 31 - blockIdx.x;          // longest-K blocks first
    int q0 = qt * 64;
    int t = threadIdx.x;
    int w = t >> 6, lane = t & 63, quad = lane >> 4, lane16 = lane & 15;
    int qw = (w & 1) * 32, vw = (w >> 1) * 32;

    const unsigned short* Pb = Pbuf + ((size_t)b * NTRI + (size_t)qt * (qt + 1) / 2) * 4096;
    const unsigned short* Vb = Vnt + (size_t)b * CDIM * TSEQ;   // [v][s]

    f32x4 acc[2][2];
    acc[0][0] = fzero(); acc[0][1] = fzero(); acc[1][0] = fzero(); acc[1][1] = fzero();

    int arow = t >> 2, aq8 = (t & 3) * 8;     // staging: row 0..63, 8-short quarter
    int Kend = (qt + 1) * 64;

    for (int k0 = 0; k0 < Kend; k0 += 32) {
        int st = k0 >> 6, kin = k0 & 32;
        gl2lds16(Pb + (size_t)st * 4096 + arow * 64 + kin + aq8, &As[t * 8]);
        gl2lds16(Vb + (size_t)(v0 + arow) * TSEQ + k0 + aq8,     &Bs[t * 8]);
        __syncthreads();

        bf16x8 a0 = *(const bf16x8*)&As[(qw + lane16) * 32 + quad * 8];
        bf16x8 a1 = *(const bf16x8*)&As[(qw + 16 + lane16) * 32 + quad * 8];
        bf16x8 b0 = *(const bf16x8*)&Bs[(vw + lane16) * 32 + quad * 8];
        bf16x8 b1 = *(const bf16x8*)&Bs[(vw + 16 + lane16) * 32 + quad * 8];
        acc[0][0] = __builtin_amdgcn_mfma_f32_16x16x32_bf16(a0, b0, acc[0][0], 0, 0, 0);
        acc[0][1] = __builtin_amdgcn_mfma_f32_16x16x32_bf16(a0, b1, acc[0][1], 0, 0, 0);
        acc[1][0] = __builtin_amdgcn_mfma_f32_16x16x32_bf16(a1, b0, acc[1][0], 0, 0, 0);
        acc[1][1] = __builtin_amdgcn_mfma_f32_16x16x32_bf16(a1, b1, acc[1][1], 0, 0, 0);
        __syncthreads();
    }

#pragma unroll
    for (int qi = 0; qi < 2; qi++) {
#pragma unroll
        for (int vi = 0; vi < 2; vi++) {
#pragma unroll
            for (int r = 0; r < 4; r++) {
                int q   = q0 + qw + qi * 16 + quad * 4 + r;
                int col = 512 + v0 + vw + vi * 16 + lane16;
                out[((size_t)b * TSEQ + q) * 1024 + col] = acc[qi][vi][r];
            }
        }
    }
}

extern "C" void kernel_launch(void* const* d_in, const int* in_sizes, int n_in,
                              void* d_out, int out_size, void* d_ws, size_t ws_size,
                              hipStream_t stream) {
    const float* x  = (const float*)d_in[0];
    const float* Wq = (const float*)d_in[1];
    const float* bq = (const float*)d_in[2];
    const float* Wk = (const float*)d_in[3];
    const float* bk = (const float*)d_in[4];
    const float* Wv = (const float*)d_in[5];
    const float* bv = (const float*)d_in[6];
    float* out = (float*)d_out;

    char* ws = (char*)d_ws;
    size_t off = 0;
    auto alloc = [&](size_t bytes) -> void* {
        void* p = ws + off;
        off += (bytes + 255) & ~(size_t)255;
        return p;
    };
    unsigned short* Qb  = (unsigned short*)alloc((size_t)MTOK * CDIM * 2);
    unsigned short* Kb  = (unsigned short*)alloc((size_t)MTOK * CDIM * 2);
    unsigned short* Vtb = (unsigned short*)alloc((size_t)MTOK * CDIM * 2);
    float* colsum = (float*)alloc((size_t)BATCH * TSEQ * 4);
    size_t xb_off = off;                 // xb/W region is dead after k_qkv;
    unsigned short* xb  = (unsigned short*)alloc((size_t)MTOK * CDIM * 2);
    unsigned short* Wqb = (unsigned short*)alloc((size_t)CDIM * CDIM * 2);
    unsigned short* Wkb = (unsigned short*)alloc((size_t)CDIM * CDIM * 2);
    unsigned short* Wvb = (unsigned short*)alloc((size_t)CDIM * CDIM * 2);
    // P tiles alias over the dead xb/W region: [b][tri][64*64] bf16 = 34.6 MB
    unsigned short* Pbuf = (unsigned short*)(ws + xb_off);

    // Stage 1: conversions (+ copy x into out[:, :, 0:512])
    k_convert_x<<<(MTOK * CDIM / 4) / 256, 256, 0, stream>>>(x, xb, out);
    k_convert_w<<<(CDIM * CDIM / 4) / 256, 256, 0, stream>>>(Wq, Wqb);
    k_convert_w<<<(CDIM * CDIM / 4) / 256, 256, 0, stream>>>(Wk, Wkb);
    k_convert_w<<<(CDIM * CDIM / 4) / 256, 256, 0, stream>>>(Wv, Wvb);

    // Stage 2: QKV projections (V stored transposed per batch: Vt[b][v][t])
    dim3 gq(MTOK / 64, CDIM / 64);
    k_qkv<<<gq, 256, 0, stream>>>(xb, Wqb, bq, Qb, 0);
    k_qkv<<<gq, 256, 0, stream>>>(xb, Wkb, bk, Kb, 1);
    k_qkv<<<gq, 256, 0, stream>>>(xb, Wvb, bv, Vtb, 2);

    // Stage 3: S over triangle -> P tiles (bf16) + column sums of exp
    hipMemsetAsync(colsum, 0, (size_t)BATCH * TSEQ * 4, stream);
    k_score<<<dim3(NTRI, BATCH), 256, 0, stream>>>(Qb, Kb, Pbuf, colsum);

    // Stage 3b/3c: fold softmax denominator into V rows
    k_invcs<<<(BATCH * TSEQ) / 256, 256, 0, stream>>>(colsum);
    k_vscale<<<(MTOK * CDIM / 8) / 256, 256, 0, stream>>>(Vtb, colsum);

    // Stage 4: attn = P @ Vn^T
    k_attn_gemm<<<dim3(TSEQ / 64, CDIM / 64, BATCH), 256, 0, stream>>>(Pbuf, Vtb, out);
}

// Round 3
// 262.898 us; speedup vs baseline: 4.0511x; 2.1757x over previous
//
#include <hip/hip_runtime.h>

// Problem constants (B=8, T=2048, C=512, KEY=512)
#define BATCH 8
#define TSEQ  2048
#define CDIM  512
#define MTOK  (BATCH*TSEQ)   // 16384
#define NTRI  136            // 16*17/2 triangular 128x128 tiles per batch

typedef __attribute__((ext_vector_type(8))) short bf16x8;
typedef __attribute__((ext_vector_type(4))) float f32x4;

__device__ __forceinline__ unsigned short f2bf(float f) {
    union { float f; unsigned int u; } v; v.f = f;
    unsigned int r = v.u + 0x7FFF + ((v.u >> 16) & 1);
    return (unsigned short)(r >> 16);
}
__device__ __forceinline__ float bfl(unsigned short u) {
    union { unsigned int i; float f; } v; v.i = ((unsigned int)u) << 16; return v.f;
}

__device__ __forceinline__ f32x4 fzero() { f32x4 z = {0.f, 0.f, 0.f, 0.f}; return z; }

// async 16B global -> LDS (LDS side is wave-uniform base + lane*16)
__device__ __forceinline__ void gl2lds16(const void* g, void* l) {
    __builtin_amdgcn_global_load_lds(
        (const __attribute__((address_space(1))) unsigned int*)g,
        (__attribute__((address_space(3))) unsigned int*)l, 16, 0, 0);
}

// stage a 128x32 bf16 tile (src = &tile[0][0], row stride ld shorts) into buf[4096]
// LDS layout: row-major [128][32]; thread t covers rows (t>>2) and 64+(t>>2).
__device__ __forceinline__ void stage_tile(const unsigned short* src, size_t ld,
                                           unsigned short* buf, int t) {
    const unsigned short* s0 = src + (size_t)(t >> 2) * ld + (t & 3) * 8;
    gl2lds16(s0, &buf[t * 8]);
    gl2lds16(s0 + (size_t)64 * ld, &buf[2048 + t * 8]);
}

// ---------------- Stage 1: conversions ----------------
__global__ __launch_bounds__(256) void k_convert_x(const float* __restrict__ x,
                                                   unsigned short* __restrict__ xb,
                                                   float* __restrict__ out) {
    int i = blockIdx.x * blockDim.x + threadIdx.x;      // float4 index
    float4 v = ((const float4*)x)[i];
    ushort4 o;
    o.x = f2bf(v.x); o.y = f2bf(v.y); o.z = f2bf(v.z); o.w = f2bf(v.w);
    ((ushort4*)xb)[i] = o;
    int e = i * 4;
    int row = e >> 9;          // /512
    int c   = e & 511;
    *(float4*)(out + (size_t)row * 1024 + c) = v;
}

__global__ __launch_bounds__(256) void k_convert_w(const float* __restrict__ w,
                                                   unsigned short* __restrict__ wb) {
    int i = blockIdx.x * blockDim.x + threadIdx.x;
    float4 v = ((const float4*)w)[i];
    ushort4 o;
    o.x = f2bf(v.x); o.y = f2bf(v.y); o.z = f2bf(v.z); o.w = f2bf(v.w);
    ((ushort4*)wb)[i] = o;
}

// ---------------- Stage 2: fused QKV projection (m97-style 128x128 GEMM) ----
// A = xb[16384,512], B = Wcat[1536,512] (Q|K|V). Output:
//   n<1024  -> QKb[m][n] (Q cols 0..511, K cols 512..1023), row-major bf16
//   n>=1024 -> Vt[b][v][t] transposed via per-wave LDS buffers
__global__ __launch_bounds__(256) void k_qkv(const unsigned short* __restrict__ xb,
                                             const unsigned short* __restrict__ Wcat,
                                             const float* __restrict__ bq,
                                             const float* __restrict__ bk,
                                             const float* __restrict__ bv,
                                             unsigned short* __restrict__ QKb,
                                             unsigned short* __restrict__ Vt) {
    __shared__ __align__(16) unsigned short lds[8192];
    unsigned short* As = lds;
    unsigned short* Bs = lds + 4096;
    int m0 = blockIdx.x * 128, n0 = blockIdx.y * 128;
    int t = threadIdx.x, w = t >> 6, lane = t & 63, quad = lane >> 4, lane16 = lane & 15;
    int rowHalf = (w >> 1) * 64, colHalf = (w & 1) * 64;

    f32x4 acc[4][4];
#pragma unroll
    for (int i = 0; i < 4; i++)
#pragma unroll
        for (int j = 0; j < 4; j++) acc[i][j] = fzero();

    for (int k0 = 0; k0 < CDIM; k0 += 32) {
        stage_tile(xb + (size_t)m0 * 512 + k0, 512, As, t);
        stage_tile(Wcat + (size_t)n0 * 512 + k0, 512, Bs, t);
        __syncthreads();
        bf16x8 a[4], b[4];
#pragma unroll
        for (int mi = 0; mi < 4; mi++)
            a[mi] = *(const bf16x8*)&As[(rowHalf + mi * 16 + lane16) * 32 + quad * 8];
#pragma unroll
        for (int ni = 0; ni < 4; ni++)
            b[ni] = *(const bf16x8*)&Bs[(colHalf + ni * 16 + lane16) * 32 + quad * 8];
#pragma unroll
        for (int mi = 0; mi < 4; mi++)
#pragma unroll
            for (int ni = 0; ni < 4; ni++)
                acc[mi][ni] = __builtin_amdgcn_mfma_f32_16x16x32_bf16(a[mi], b[ni], acc[mi][ni], 0, 0, 0);
        __syncthreads();
    }

    int which = n0 >> 9;     // block-uniform: 0=Q, 1=K, 2=V
    if (which < 2) {
        const float* bias = which ? bk : bq;
#pragma unroll
        for (int ni = 0; ni < 4; ni++) {
            int n = (n0 & 511) + colHalf + ni * 16 + lane16;
            float bb = bias[n];
            int col = which * 512 + n;
#pragma unroll
            for (int mi = 0; mi < 4; mi++)
#pragma unroll
                for (int r = 0; r < 4; r++) {
                    int m = m0 + rowHalf + mi * 16 + quad * 4 + r;
                    QKb[(size_t)m * 1024 + col] = f2bf(acc[mi][ni][r] + bb);
                }
        }
    } else {
        // V: transpose 64x64 wave quadrant -> Vt[b][v][t] in two 32-col passes
        unsigned short* T = &lds[w * 2048];        // [32 v][64 t]
        int b = m0 >> 11, tbase = (m0 & 2047) + rowHalf;
#pragma unroll
        for (int p = 0; p < 2; p++) {
            __syncthreads();
#pragma unroll
            for (int j = 0; j < 2; j++) {
                int ni = p * 2 + j;
                int n = (n0 & 511) + colHalf + ni * 16 + lane16;
                float bb = bv[n];
                int vl = j * 16 + lane16;
#pragma unroll
                for (int mi = 0; mi < 4; mi++)
#pragma unroll
                    for (int r = 0; r < 4; r++)
                        T[vl * 64 + mi * 16 + quad * 4 + r] = f2bf(acc[mi][ni][r] + bb);
            }
            __syncthreads();
#pragma unroll
            for (int i = 0; i < 4; i++) {
                int vl = i * 8 + (lane >> 3);
                int tl = (lane & 7) * 8;
                int v = (n0 & 511) + colHalf + p * 32 + vl;
                *(uint4*)(Vt + ((size_t)(b * 512 + v)) * 2048 + tbase + tl) =
                    *(const uint4*)&T[vl * 64 + tl];
            }
        }
    }
}

// ---------------- Stage 3: S = QK^T over triangle; P tiles (128x128) + colsum
__global__ __launch_bounds__(256) void k_score(const unsigned short* __restrict__ QKb,
                                               unsigned short* __restrict__ Pbuf,
                                               float* __restrict__ colsum) {
    __shared__ __align__(16) unsigned short lds[16384];   // staging 16KB / P-out 32KB
    unsigned short* As = lds;
    unsigned short* Bs = lds + 4096;
    int idx = blockIdx.x, bb = blockIdx.y;
    int qt = (int)((sqrtf(8.0f * idx + 1.0f) - 1.0f) * 0.5f);
    while ((qt + 1) * (qt + 2) / 2 <= idx) qt++;
    while (qt * (qt + 1) / 2 > idx) qt--;
    int st = idx - qt * (qt + 1) / 2;
    int q0 = qt * 128, s0 = st * 128;

    int t = threadIdx.x, w = t >> 6, lane = t & 63, quad = lane >> 4, lane16 = lane & 15;
    int rowHalf = (w >> 1) * 64, colHalf = (w & 1) * 64;
    const unsigned short* Qrows = QKb + ((size_t)(bb * 2048 + q0)) * 1024;
    const unsigned short* Krows = QKb + ((size_t)(bb * 2048 + s0)) * 1024 + 512;

    f32x4 acc[4][4];
#pragma unroll
    for (int i = 0; i < 4; i++)
#pragma unroll
        for (int j = 0; j < 4; j++) acc[i][j] = fzero();

    for (int k0 = 0; k0 < CDIM; k0 += 32) {
        stage_tile(Qrows + k0, 1024, As, t);
        stage_tile(Krows + k0, 1024, Bs, t);
        __syncthreads();
        bf16x8 a[4], b[4];
#pragma unroll
        for (int mi = 0; mi < 4; mi++)
            a[mi] = *(const bf16x8*)&As[(rowHalf + mi * 16 + lane16) * 32 + quad * 8];
#pragma unroll
        for (int ni = 0; ni < 4; ni++)
            b[ni] = *(const bf16x8*)&Bs[(colHalf + ni * 16 + lane16) * 32 + quad * 8];
#pragma unroll
        for (int mi = 0; mi < 4; mi++)
#pragma unroll
            for (int ni = 0; ni < 4; ni++)
                acc[mi][ni] = __builtin_amdgcn_mfma_f32_16x16x32_bf16(a[mi], b[ni], acc[mi][ni], 0, 0, 0);
        __syncthreads();
    }

    // epilogue: exp + mask + column sums + P through per-wave LDS quadrant
    const float scale = 0.044194173824159216f;  // 1/sqrt(512)
    unsigned short* T = &lds[w * 4096];         // [64 q][64 s] per wave
    float csum[4] = {0.f, 0.f, 0.f, 0.f};
#pragma unroll
    for (int ni = 0; ni < 4; ni++) {
        int s = s0 + colHalf + ni * 16 + lane16;
#pragma unroll
        for (int mi = 0; mi < 4; mi++)
#pragma unroll
            for (int r = 0; r < 4; r++) {
                int q = q0 + rowHalf + mi * 16 + quad * 4 + r;
                float p = 0.0f;
                if (s <= q) { p = __expf(acc[mi][ni][r] * scale); csum[ni] += p; }
                T[(mi * 16 + quad * 4 + r) * 64 + ni * 16 + lane16] = f2bf(p);
            }
    }
#pragma unroll
    for (int ni = 0; ni < 4; ni++) {
        float v = csum[ni];
        v += __shfl_xor(v, 16);
        v += __shfl_xor(v, 32);
        if (quad == 0)
            atomicAdd(&colsum[bb * 2048 + s0 + colHalf + ni * 16 + lane16], v);
    }
    __syncthreads();
    unsigned short* tile = Pbuf + ((size_t)(bb * NTRI + idx)) * 16384;
#pragma unroll
    for (int i = 0; i < 8; i++) {
        int rl = i * 8 + (lane >> 3);
        int cl = (lane & 7) * 8;
        *(uint4*)(tile + (rowHalf + rl) * 128 + colHalf + cl) = *(const uint4*)&T[rl * 64 + cl];
    }
}

// ---------------- Stage 3b: invert colsum ----------------
__global__ __launch_bounds__(256) void k_invcs(float* __restrict__ cs) {
    int i = blockIdx.x * 256 + threadIdx.x;
    cs[i] = 1.0f / cs[i];
}

// ---------------- Stage 3c: Vn[v][s] = V[v][s] * inv_colsum[s] (in place) ---
__global__ __launch_bounds__(256) void k_vscale(unsigned short* __restrict__ Vt,
                                                const float* __restrict__ inv) {
    int idx = blockIdx.x * 256 + threadIdx.x;   // 16B unit (8 bf16)
    int s8  = idx & 255;                        // 2048/8 units per row
    int row = idx >> 8;                         // b*512 + v
    int b   = row >> 9;
    uint4 raw = ((const uint4*)Vt)[idx];
    const float* ip = inv + b * TSEQ + s8 * 8;
    unsigned int rr[4] = {raw.x, raw.y, raw.z, raw.w};
    unsigned int oo[4];
#pragma unroll
    for (int j = 0; j < 4; j++) {
        float f0 = bfl((unsigned short)(rr[j] & 0xffff)) * ip[j * 2];
        float f1 = bfl((unsigned short)(rr[j] >> 16))    * ip[j * 2 + 1];
        oo[j] = (unsigned int)f2bf(f0) | ((unsigned int)f2bf(f1) << 16);
    }
    uint4 o = {oo[0], oo[1], oo[2], oo[3]};
    ((uint4*)Vt)[idx] = o;
}

// ---------------- Stage 4: attn = P @ Vn^T (128x128 GEMM, longest-K first) --
__global__ __launch_bounds__(256) void k_attn(const unsigned short* __restrict__ Pbuf,
                                              const unsigned short* __restrict__ Vt,
                                              float* __restrict__ out) {
    __shared__ __align__(16) unsigned short lds[8192];
    unsigned short* As = lds;
    unsigned short* Bs = lds + 4096;
    int qt = 15 - blockIdx.x;           // longest-K blocks first
    int v0 = blockIdx.y * 128;
    int bb = blockIdx.z;
    int t = threadIdx.x, w = t >> 6, lane = t & 63, quad = lane >> 4, lane16 = lane & 15;
    int rowHalf = (w >> 1) * 64, colHalf = (w & 1) * 64;

    const unsigned short* Pb = Pbuf + ((size_t)(bb * NTRI + qt * (qt + 1) / 2)) * 16384;
    const unsigned short* Vb = Vt + ((size_t)(bb * 512 + v0)) * 2048;

    f32x4 acc[4][4];
#pragma unroll
    for (int i = 0; i < 4; i++)
#pragma unroll
        for (int j = 0; j < 4; j++) acc[i][j] = fzero();

    int Kend = (qt + 1) * 128;
    for (int k0 = 0; k0 < Kend; k0 += 32) {
        int stt = k0 >> 7, kin = k0 & 127;
        stage_tile(Pb + (size_t)stt * 16384 + kin, 128, As, t);
        stage_tile(Vb + k0, 2048, Bs, t);
        __syncthreads();
        bf16x8 a[4], b[4];
#pragma unroll
        for (int mi = 0; mi < 4; mi++)
            a[mi] = *(const bf16x8*)&As[(rowHalf + mi * 16 + lane16) * 32 + quad * 8];
#pragma unroll
        for (int ni = 0; ni < 4; ni++)
            b[ni] = *(const bf16x8*)&Bs[(colHalf + ni * 16 + lane16) * 32 + quad * 8];
#pragma unroll
        for (int mi = 0; mi < 4; mi++)
#pragma unroll
            for (int ni = 0; ni < 4; ni++)
                acc[mi][ni] = __builtin_amdgcn_mfma_f32_16x16x32_bf16(a[mi], b[ni], acc[mi][ni], 0, 0, 0);
        __syncthreads();
    }

#pragma unroll
    for (int mi = 0; mi < 4; mi++)
#pragma unroll
        for (int ni = 0; ni < 4; ni++)
#pragma unroll
            for (int r = 0; r < 4; r++) {
                int q = qt * 128 + rowHalf + mi * 16 + quad * 4 + r;
                int v = v0 + colHalf + ni * 16 + lane16;
                out[((size_t)(bb * 2048 + q)) * 1024 + 512 + v] = acc[mi][ni][r];
            }
}

extern "C" void kernel_launch(void* const* d_in, const int* in_sizes, int n_in,
                              void* d_out, int out_size, void* d_ws, size_t ws_size,
                              hipStream_t stream) {
    const float* x  = (const float*)d_in[0];
    const float* Wq = (const float*)d_in[1];
    const float* bq = (const float*)d_in[2];
    const float* Wk = (const float*)d_in[3];
    const float* bk = (const float*)d_in[4];
    const float* Wv = (const float*)d_in[5];
    const float* bv = (const float*)d_in[6];
    float* out = (float*)d_out;

    char* ws = (char*)d_ws;
    size_t off = 0;
    auto alloc = [&](size_t bytes) -> void* {
        void* p = ws + off;
        off += (bytes + 255) & ~(size_t)255;
        return p;
    };
    // live through the whole pipeline:
    unsigned short* QKb = (unsigned short*)alloc((size_t)MTOK * 1024 * 2);   // 33.5 MB
    unsigned short* Vt  = (unsigned short*)alloc((size_t)MTOK * CDIM * 2);   // 16.8 MB
    float* colsum = (float*)alloc((size_t)BATCH * TSEQ * 4);
    // dead after k_qkv -> Pbuf aliases from here (needs 35.65 MB):
    size_t mark = off;
    unsigned short* Wcat = (unsigned short*)alloc((size_t)3 * CDIM * CDIM * 2);
    unsigned short* xb   = (unsigned short*)alloc((size_t)MTOK * CDIM * 2);
    unsigned short* Pbuf = (unsigned short*)(ws + mark);
    (void)ws_size;

    // Stage 1: conversions (+ copy x into out[:, :, 0:512])
    k_convert_x<<<(MTOK * CDIM / 4) / 256, 256, 0, stream>>>(x, xb, out);
    k_convert_w<<<(CDIM * CDIM / 4) / 256, 256, 0, stream>>>(Wq, Wcat);
    k_convert_w<<<(CDIM * CDIM / 4) / 256, 256, 0, stream>>>(Wk, Wcat + (size_t)CDIM * CDIM);
    k_convert_w<<<(CDIM * CDIM / 4) / 256, 256, 0, stream>>>(Wv, Wcat + (size_t)2 * CDIM * CDIM);

    // Stage 2: fused QKV projection
    k_qkv<<<dim3(MTOK / 128, 1536 / 128), 256, 0, stream>>>(xb, Wcat, bq, bk, bv, QKb, Vt);

    // Stage 3: S over triangle -> P tiles (bf16) + column sums of exp
    hipMemsetAsync(colsum, 0, (size_t)BATCH * TSEQ * 4, stream);
    k_score<<<dim3(NTRI, BATCH), 256, 0, stream>>>(QKb, Pbuf, colsum);

    // Stage 3b/3c: fold softmax denominator into V rows
    k_invcs<<<(BATCH * TSEQ) / 256, 256, 0, stream>>>(colsum);
    k_vscale<<<(MTOK * CDIM / 8) / 256, 256, 0, stream>>>(Vt, colsum);

    // Stage 4: attn = P @ Vn^T
    k_attn<<<dim3(16, CDIM / 128, BATCH), 256, 0, stream>>>(Pbuf, Vt, out);
}